// Round 3
// baseline (31.693 us; speedup 1.0000x reference)
//
#include <hip/hip_runtime.h>
#include <math.h>

#define MM 8192
#define NN 64
#define NB 25
#define NBP 28          // padded bone records per m (28 = 7 groups of 4)
#define KS 12           // floats per K record (10 used + 2 pad, 48B aligned)
#define QS 8            // floats per Q record (qr, qd)
#define LOG2E 1.44269504088896340736f

struct Q { float w, x, y, z; };

__device__ __forceinline__ Q qmul(const Q a, const Q b) {
    Q r;
    r.w = a.w*b.w - a.x*b.x - a.y*b.y - a.z*b.z;
    r.x = a.w*b.x + b.w*a.x + a.y*b.z - a.z*b.y;
    r.y = a.w*b.y + b.w*a.y + a.z*b.x - a.x*b.z;
    r.z = a.w*b.z + b.w*a.z + a.x*b.y - a.y*b.x;
    return r;
}

// ---------------- kernel A: per-(m,bone) record precompute ----------------
__global__ __launch_bounds__(256) void prep_kernel(
    const float* __restrict__ t_qr, const float* __restrict__ t_qd,
    const float* __restrict__ rest_qr, const float* __restrict__ rest_qd,
    const float* __restrict__ log_gauss,
    float* __restrict__ Kbuf, float* __restrict__ Qbuf)
{
    const int idx = blockIdx.x * 256 + threadIdx.x;
    if (idx >= MM * NBP) return;
    const int m = idx / NBP;
    const int r = idx - m * NBP;
    const int b = (r < NB) ? r : (NB - 1);

    const int qbase = (m * NB + b) * 4;
    const float4 Tqv = *reinterpret_cast<const float4*>(t_qr + qbase);
    const float4 Tdv = *reinterpret_cast<const float4*>(t_qd + qbase);
    const float4 Rqv = *reinterpret_cast<const float4*>(rest_qr + qbase);
    const float4 Rdv = *reinterpret_cast<const float4*>(rest_qd + qbase);
    const float i0 = __expf(-log_gauss[b * 3 + 0]);
    const float i1 = __expf(-log_gauss[b * 3 + 1]);
    const float i2 = __expf(-log_gauss[b * 3 + 2]);

    const Q Tq{Tqv.x, Tqv.y, Tqv.z, Tqv.w};
    const Q Td{Tdv.x, Tdv.y, Tdv.z, Tdv.w};
    const Q Rq{Rqv.x, Rqv.y, Rqv.z, Rqv.w};
    const Q Rqc{Rq.w, -Rq.x, -Rq.y, -Rq.z};
    const Q Rdc{Rdv.x, -Rdv.y, -Rdv.z, -Rdv.w};

    // se3 = t_art * inverse(rest_art)
    const Q se_r = qmul(Tq, Rqc);
    const Q m1 = qmul(Tq, Rdc);
    const Q m2 = qmul(Td, Rqc);
    const Q se_d{m1.w + m2.w, m1.x + m2.x, m1.y + m2.y, m1.z + m2.z};

    // hemisphere sign vs bone 0 of the same m (recomputed locally)
    const int b0 = m * NB * 4;
    const float4 Tq0v = *reinterpret_cast<const float4*>(t_qr + b0);
    const float4 Rq0v = *reinterpret_cast<const float4*>(rest_qr + b0);
    const Q Tq0{Tq0v.x, Tq0v.y, Tq0v.z, Tq0v.w};
    const Q Rq0c{Rq0v.x, -Rq0v.y, -Rq0v.z, -Rq0v.w};
    const Q se0 = qmul(Tq0, Rq0c);
    const float d0 = se_r.w*se0.w + se_r.x*se0.x + se_r.y*se0.y + se_r.z*se0.z;
    float sg = (d0 < 0.f) ? -1.f : 1.f;
    if (r >= NB) sg = 0.f;   // dummy records contribute nothing

    // bone-inverse transform: rot = R(qconj(rest_qr)), trans = 2*vec(qmul(qconj(rest_qd), rest_qr))
    const Q tqb = qmul(Rdc, Rq);
    const float qw = Rqc.w, qx = Rqc.x, qy = Rqc.y, qz = Rqc.z;
    const float r00 = 1.f - 2.f*(qy*qy + qz*qz), r01 = 2.f*(qx*qy - qw*qz), r02 = 2.f*(qx*qz + qw*qy);
    const float r10 = 2.f*(qx*qy + qw*qz), r11 = 1.f - 2.f*(qx*qx + qz*qz), r12 = 2.f*(qy*qz - qw*qx);
    const float r20 = 2.f*(qx*qz - qw*qy), r21 = 2.f*(qy*qz + qw*qx), r22 = 1.f - 2.f*(qx*qx + qy*qy);

    const float g00 = r00*i0, g01 = r01*i0, g02 = r02*i0;
    const float g10 = r10*i1, g11 = r11*i1, g12 = r12*i1;
    const float g20 = r20*i2, g21 = r21*i2, g22 = r22*i2;
    const float u0 = 2.f*tqb.x*i0, u1 = 2.f*tqb.y*i1, u2 = 2.f*tqb.z*i2;

    // logit_log2(p) = LOG2E * (-0.5*|Gp+u|^2) as quadratic form
    const float c = LOG2E;
    float k0 = -0.5f*c*(g00*g00 + g10*g10 + g20*g20);
    float k1 = -0.5f*c*(g01*g01 + g11*g11 + g21*g21);
    float k2 = -0.5f*c*(g02*g02 + g12*g12 + g22*g22);
    float k3 = -c*(g00*g01 + g10*g11 + g20*g21);
    float k4 = -c*(g00*g02 + g10*g12 + g20*g22);
    float k5 = -c*(g01*g02 + g11*g12 + g21*g22);
    float k6 = -c*(g00*u0 + g10*u1 + g20*u2);
    float k7 = -c*(g01*u0 + g11*u1 + g21*u2);
    float k8 = -c*(g02*u0 + g12*u1 + g22*u2);
    float k9 = -0.5f*c*(u0*u0 + u1*u1 + u2*u2);
    if (r >= NB) k9 = -1.0e9f;

    float* kp = Kbuf + (size_t)idx * KS;
    *reinterpret_cast<float4*>(kp + 0) = make_float4(k0, k1, k2, k3);
    *reinterpret_cast<float4*>(kp + 4) = make_float4(k4, k5, k6, k7);
    *reinterpret_cast<float4*>(kp + 8) = make_float4(k8, k9, 0.f, 0.f);
    float* qp = Qbuf + (size_t)idx * QS;
    *reinterpret_cast<float4*>(qp + 0) = make_float4(sg*se_r.w, sg*se_r.x, sg*se_r.y, sg*se_r.z);
    *reinterpret_cast<float4*>(qp + 4) = make_float4(sg*se_d.w, sg*se_d.x, sg*se_d.y, sg*se_d.z);
}

// ---------------- kernel B: one wave per m; bone records via scalar loads ----------------
__global__ __launch_bounds__(64) void skin_kernel(
    const float* __restrict__ xyz,
    const float* __restrict__ Kbuf,
    const float* __restrict__ Qbuf,
    float* __restrict__ out)
{
    const int m = blockIdx.x;          // wave-uniform -> s_load path for bone records
    const int lane = threadIdx.x;      // 0..63, one point per lane
    const float* __restrict__ Kp = Kbuf + (size_t)m * NBP * KS;
    const float* __restrict__ Qp = Qbuf + (size_t)m * NBP * QS;

    const int pbase = (m * NN + lane) * 3;
    const float px = xyz[pbase], py = xyz[pbase + 1], pz = xyz[pbase + 2];
    const float fxx = px*px, fyy = py*py, fzz = pz*pz;
    const float fxy = px*py, fxz = px*pz, fyz = py*pz;

    float logit[NBP];
    float mx = -3.4e38f;
#pragma unroll
    for (int r = 0; r < NBP; ++r) {
        const float* kp = Kp + r * KS;
        float t = fmaf(kp[8], pz, kp[9]);
        t = fmaf(kp[7], py, t);
        t = fmaf(kp[6], px, t);
        t = fmaf(kp[5], fyz, t);
        t = fmaf(kp[4], fxz, t);
        t = fmaf(kp[3], fxy, t);
        t = fmaf(kp[2], fzz, t);
        t = fmaf(kp[1], fyy, t);
        t = fmaf(kp[0], fxx, t);
        logit[r] = t;
        mx = fmaxf(mx, t);
    }

    float aw = 0.f, ax = 0.f, ay = 0.f, az = 0.f;
    float bw = 0.f, bx = 0.f, by = 0.f, bz = 0.f;
#pragma unroll
    for (int r = 0; r < NBP; ++r) {
        const float* qp = Qp + r * QS;
        const float e = __builtin_amdgcn_exp2f(logit[r] - mx);
        aw = fmaf(e, qp[0], aw);
        ax = fmaf(e, qp[1], ax);
        ay = fmaf(e, qp[2], ay);
        az = fmaf(e, qp[3], az);
        bw = fmaf(e, qp[4], bw);
        bx = fmaf(e, qp[5], bx);
        by = fmaf(e, qp[6], by);
        bz = fmaf(e, qp[7], bz);
    }

    const float inv = rsqrtf(aw*aw + ax*ax + ay*ay + az*az);
    const Q qr{aw*inv, ax*inv, ay*inv, az*inv};
    const Q qd{bw*inv, bx*inv, by*inv, bz*inv};
    const Q qrc{qr.w, -qr.x, -qr.y, -qr.z};
    const Q tq = qmul(qd, qrc);

    const float uvx = qr.y*pz - qr.z*py;
    const float uvy = qr.z*px - qr.x*pz;
    const float uvz = qr.x*py - qr.y*px;
    const float cx = qr.y*uvz - qr.z*uvy;
    const float cy = qr.z*uvx - qr.x*uvz;
    const float cz = qr.x*uvy - qr.y*uvx;

    out[pbase]     = px + 2.f*(qr.w*uvx + cx) + 2.f*tq.x;
    out[pbase + 1] = py + 2.f*(qr.w*uvy + cy) + 2.f*tq.y;
    out[pbase + 2] = pz + 2.f*(qr.w*uvz + cz) + 2.f*tq.z;
}

extern "C" void kernel_launch(void* const* d_in, const int* in_sizes, int n_in,
                              void* d_out, int out_size, void* d_ws, size_t ws_size,
                              hipStream_t stream) {
    const float* xyz       = (const float*)d_in[0];
    const float* t_qr      = (const float*)d_in[1];
    const float* t_qd      = (const float*)d_in[2];
    const float* rest_qr   = (const float*)d_in[3];
    const float* rest_qd   = (const float*)d_in[4];
    const float* log_gauss = (const float*)d_in[5];
    float* out  = (float*)d_out;
    float* Kbuf = (float*)d_ws;                                   // 8192*28*12*4 = 11,010,048 B
    float* Qbuf = (float*)((char*)d_ws + (size_t)MM * NBP * KS * 4); // + 8192*28*8*4 = 7,340,032 B

    hipLaunchKernelGGL(prep_kernel, dim3((MM * NBP + 255) / 256), dim3(256), 0, stream,
                       t_qr, t_qd, rest_qr, rest_qd, log_gauss, Kbuf, Qbuf);
    hipLaunchKernelGGL(skin_kernel, dim3(MM), dim3(64), 0, stream,
                       xyz, Kbuf, Qbuf, out);
}

// Round 4
// 23.055 us; speedup vs baseline: 1.3746x; 1.3746x over previous
//
#include <hip/hip_runtime.h>
#include <math.h>

#define MM 8192
#define NN 64
#define NB 25
#define KS 12      // K record floats (10 used, padded to 48 B for 16B-aligned s_load)
#define QS 8       // per-(m,b) record: sign-fixed qr, qd
#define LOG2E 1.44269504088896340736f

struct Q { float w, x, y, z; };

__device__ __forceinline__ Q qmul(const Q a, const Q b) {
    Q r;
    r.w = a.w*b.w - a.x*b.x - a.y*b.y - a.z*b.z;
    r.x = a.w*b.x + b.w*a.x + a.y*b.z - a.z*b.y;
    r.y = a.w*b.y + b.w*a.y + a.z*b.x - a.x*b.z;
    r.z = a.w*b.z + b.w*a.z + a.x*b.y - a.y*b.x;
    return r;
}

// ---- kernel A: per-(m,b) sign-fixed se3 quats; thread (m=0,b) also emits the global K table ----
__global__ __launch_bounds__(256) void prep_kernel(
    const float* __restrict__ t_qr, const float* __restrict__ t_qd,
    const float* __restrict__ rest_qr, const float* __restrict__ rest_qd,
    const float* __restrict__ log_gauss,
    float* __restrict__ Kbuf, float* __restrict__ Qbuf)
{
    const int idx = blockIdx.x * 256 + threadIdx.x;   // grid sized exactly MM*NB/256
    const int m = idx / NB;
    const int b = idx - m * NB;

    const int qbase = idx * 4;
    const float4 Tqv = *reinterpret_cast<const float4*>(t_qr + qbase);
    const float4 Tdv = *reinterpret_cast<const float4*>(t_qd + qbase);
    // rest_* rows are identical across m (broadcast in setup) -> read row 0 only
    const float4 Rqv = *reinterpret_cast<const float4*>(rest_qr + b * 4);
    const float4 Rdv = *reinterpret_cast<const float4*>(rest_qd + b * 4);

    const Q Tq{Tqv.x, Tqv.y, Tqv.z, Tqv.w};
    const Q Td{Tdv.x, Tdv.y, Tdv.z, Tdv.w};
    const Q Rq{Rqv.x, Rqv.y, Rqv.z, Rqv.w};
    const Q Rqc{Rq.w, -Rq.x, -Rq.y, -Rq.z};
    const Q Rdc{Rdv.x, -Rdv.y, -Rdv.z, -Rdv.w};

    // se3 = t_art * inverse(rest_art)
    const Q se_r = qmul(Tq, Rqc);
    const Q m1 = qmul(Tq, Rdc);
    const Q m2 = qmul(Td, Rqc);
    const Q se_d{m1.w + m2.w, m1.x + m2.x, m1.y + m2.y, m1.z + m2.z};

    // hemisphere sign vs bone 0 of this m
    const float4 Tq0v = *reinterpret_cast<const float4*>(t_qr + m * NB * 4);
    const float4 Rq0v = *reinterpret_cast<const float4*>(rest_qr);
    const Q Tq0{Tq0v.x, Tq0v.y, Tq0v.z, Tq0v.w};
    const Q Rq0c{Rq0v.x, -Rq0v.y, -Rq0v.z, -Rq0v.w};
    const Q se0 = qmul(Tq0, Rq0c);
    const float d0 = se_r.w*se0.w + se_r.x*se0.x + se_r.y*se0.y + se_r.z*se0.z;
    const float sg = (d0 < 0.f) ? -1.f : 1.f;

    float* qp = Qbuf + idx * QS;
    *reinterpret_cast<float4*>(qp + 0) = make_float4(sg*se_r.w, sg*se_r.x, sg*se_r.y, sg*se_r.z);
    *reinterpret_cast<float4*>(qp + 4) = make_float4(sg*se_d.w, sg*se_d.x, sg*se_d.y, sg*se_d.z);

    // global K table: depends only on rest + log_gauss -> emit once (threads of m==0)
    if (m == 0) {
        const float i0 = __expf(-log_gauss[b * 3 + 0]);
        const float i1 = __expf(-log_gauss[b * 3 + 1]);
        const float i2 = __expf(-log_gauss[b * 3 + 2]);
        const Q tqb = qmul(Rdc, Rq);   // translation of bone-inverse = 2*vec
        const float qw = Rqc.w, qx = Rqc.x, qy = Rqc.y, qz = Rqc.z;
        const float r00 = 1.f - 2.f*(qy*qy + qz*qz), r01 = 2.f*(qx*qy - qw*qz), r02 = 2.f*(qx*qz + qw*qy);
        const float r10 = 2.f*(qx*qy + qw*qz), r11 = 1.f - 2.f*(qx*qx + qz*qz), r12 = 2.f*(qy*qz - qw*qx);
        const float r20 = 2.f*(qx*qz - qw*qy), r21 = 2.f*(qy*qz + qw*qx), r22 = 1.f - 2.f*(qx*qx + qy*qy);
        const float g00 = r00*i0, g01 = r01*i0, g02 = r02*i0;
        const float g10 = r10*i1, g11 = r11*i1, g12 = r12*i1;
        const float g20 = r20*i2, g21 = r21*i2, g22 = r22*i2;
        const float u0 = 2.f*tqb.x*i0, u1 = 2.f*tqb.y*i1, u2 = 2.f*tqb.z*i2;
        const float c = LOG2E;
        float* kp = Kbuf + b * KS;
        *reinterpret_cast<float4*>(kp + 0) = make_float4(
            -0.5f*c*(g00*g00 + g10*g10 + g20*g20),
            -0.5f*c*(g01*g01 + g11*g11 + g21*g21),
            -0.5f*c*(g02*g02 + g12*g12 + g22*g22),
            -c*(g00*g01 + g10*g11 + g20*g21));
        *reinterpret_cast<float4*>(kp + 4) = make_float4(
            -c*(g00*g02 + g10*g12 + g20*g22),
            -c*(g01*g02 + g11*g12 + g21*g22),
            -c*(g00*u0 + g10*u1 + g20*u2),
            -c*(g01*u0 + g11*u1 + g21*u2));
        *reinterpret_cast<float4*>(kp + 8) = make_float4(
            -c*(g02*u0 + g12*u1 + g22*u2),
            -0.5f*c*(u0*u0 + u1*u1 + u2*u2), 0.f, 0.f);
    }
}

// ---- kernel B: 4 waves/block, wave->m; bone data via SMEM (scalar) pipe, zero LDS ----
__global__ __launch_bounds__(256) void skin_kernel(
    const float* __restrict__ xyz,
    const float* __restrict__ Kbuf,
    const float* __restrict__ Qbuf,
    float* __restrict__ out)
{
    const int wave = threadIdx.x >> 6;
    const int lane = threadIdx.x & 63;
    const int m = blockIdx.x * 4 + wave;
    const int mu = __builtin_amdgcn_readfirstlane(m);          // force SGPR -> s_load path
    const float* __restrict__ Qp = Qbuf + mu * (NB * QS);

    const int pbase = (m * NN + lane) * 3;
    const float px = xyz[pbase], py = xyz[pbase + 1], pz = xyz[pbase + 2];
    const float fxx = px*px, fyy = py*py, fzz = pz*pz;
    const float fxy = px*py, fxz = px*pz, fyz = py*pz;

    float logit[NB];
    float mx = -3.4e38f;
#pragma unroll
    for (int b = 0; b < NB; ++b) {
        const float* kp = Kbuf + b * KS;                        // literally-uniform address
        float t = fmaf(kp[8], pz, kp[9]);
        t = fmaf(kp[7], py, t);
        t = fmaf(kp[6], px, t);
        t = fmaf(kp[5], fyz, t);
        t = fmaf(kp[4], fxz, t);
        t = fmaf(kp[3], fxy, t);
        t = fmaf(kp[2], fzz, t);
        t = fmaf(kp[1], fyy, t);
        t = fmaf(kp[0], fxx, t);
        logit[b] = t;
        mx = fmaxf(mx, t);
    }

    float aw = 0.f, ax = 0.f, ay = 0.f, az = 0.f;
    float bw = 0.f, bx = 0.f, by = 0.f, bz = 0.f;
#pragma unroll
    for (int b = 0; b < NB; ++b) {
        const float* qp = Qp + b * QS;                          // SGPR base + imm offsets
        const float e = __builtin_amdgcn_exp2f(logit[b] - mx);
        aw = fmaf(e, qp[0], aw);
        ax = fmaf(e, qp[1], ax);
        ay = fmaf(e, qp[2], ay);
        az = fmaf(e, qp[3], az);
        bw = fmaf(e, qp[4], bw);
        bx = fmaf(e, qp[5], bx);
        by = fmaf(e, qp[6], by);
        bz = fmaf(e, qp[7], bz);
    }

    const float inv = rsqrtf(aw*aw + ax*ax + ay*ay + az*az);
    const Q qr{aw*inv, ax*inv, ay*inv, az*inv};
    const Q qd{bw*inv, bx*inv, by*inv, bz*inv};
    const Q qrc{qr.w, -qr.x, -qr.y, -qr.z};
    const Q tq = qmul(qd, qrc);

    const float uvx = qr.y*pz - qr.z*py;
    const float uvy = qr.z*px - qr.x*pz;
    const float uvz = qr.x*py - qr.y*px;
    const float cx = qr.y*uvz - qr.z*uvy;
    const float cy = qr.z*uvx - qr.x*uvz;
    const float cz = qr.x*uvy - qr.y*uvx;

    out[pbase]     = px + 2.f*(qr.w*uvx + cx) + 2.f*tq.x;
    out[pbase + 1] = py + 2.f*(qr.w*uvy + cy) + 2.f*tq.y;
    out[pbase + 2] = pz + 2.f*(qr.w*uvz + cz) + 2.f*tq.z;
}

extern "C" void kernel_launch(void* const* d_in, const int* in_sizes, int n_in,
                              void* d_out, int out_size, void* d_ws, size_t ws_size,
                              hipStream_t stream) {
    const float* xyz       = (const float*)d_in[0];
    const float* t_qr      = (const float*)d_in[1];
    const float* t_qd      = (const float*)d_in[2];
    const float* rest_qr   = (const float*)d_in[3];
    const float* rest_qd   = (const float*)d_in[4];
    const float* log_gauss = (const float*)d_in[5];
    float* out  = (float*)d_out;
    float* Kbuf = (float*)d_ws;                       // 25*12*4 = 1200 B
    float* Qbuf = (float*)((char*)d_ws + 4096);       // 8192*25*8*4 = 6.55 MB

    hipLaunchKernelGGL(prep_kernel, dim3(MM * NB / 256), dim3(256), 0, stream,
                       t_qr, t_qd, rest_qr, rest_qd, log_gauss, Kbuf, Qbuf);
    hipLaunchKernelGGL(skin_kernel, dim3(MM / 4), dim3(256), 0, stream,
                       xyz, Kbuf, Qbuf, out);
}

// Round 6
// 15.630 us; speedup vs baseline: 2.0277x; 1.4751x over previous
//
#include <hip/hip_runtime.h>
#include <hip/hip_fp16.h>
#include <math.h>

#define MM 8192
#define NN 64
#define NB 25
#define MPB 16              // m's per block
#define PPT 4               // points per thread
#define LOG2E 1.44269504088896340736f

struct Q { float w, x, y, z; };

__device__ __forceinline__ Q qmul(const Q a, const Q b) {
    Q r;
    r.w = a.w*b.w - a.x*b.x - a.y*b.y - a.z*b.z;
    r.x = a.w*b.x + b.w*a.x + a.y*b.z - a.z*b.y;
    r.y = a.w*b.y + b.w*a.y + a.z*b.x - a.x*b.z;
    r.z = a.w*b.z + b.w*a.z + a.x*b.y - a.y*b.x;
    return r;
}

__device__ __forceinline__ unsigned pk_rn(float a, float b) {
    return __builtin_bit_cast(unsigned, __floats2half2_rn(a, b));
}

typedef __fp16 f16x2 __attribute__((ext_vector_type(2)));
__device__ __forceinline__ __half2 pk_rtz(float a, float b) {
    f16x2 v = __builtin_amdgcn_cvt_pkrtz(a, b);
    return __builtin_bit_cast(__half2, v);
}
__device__ __forceinline__ __half2 bc_h2(unsigned u) {
    return __builtin_bit_cast(__half2, u);
}

__global__ __launch_bounds__(256, 2) void skin_kernel(
    const float* __restrict__ xyz,
    const float* __restrict__ t_qr,
    const float* __restrict__ t_qd,
    const float* __restrict__ rest_qr,
    const float* __restrict__ rest_qd,
    const float* __restrict__ log_gauss,
    float* __restrict__ out)
{
    __shared__ __align__(16) float   kK[NB][12];          // fp32 quadratic-form coeffs (global-const, per-block recompute)
    __shared__ __align__(16) float   sref[MPB][4];        // bone-0 se_r per m (for hemisphere sign)
    __shared__ __align__(16) unsigned qQ[MPB][NB][4];     // packed fp16 (qr,qd) per (m,b)

    const int t  = threadIdx.x;
    const int m0 = blockIdx.x * MPB;

    // ---------- phase 0: K table (depends only on rest row 0 + log_gauss) ----------
    if (t < NB) {
        const int b = t;
        const float4 Rqv = *reinterpret_cast<const float4*>(rest_qr + b * 4);
        const float4 Rdv = *reinterpret_cast<const float4*>(rest_qd + b * 4);
        const Q Rq{Rqv.x, Rqv.y, Rqv.z, Rqv.w};
        const Q Rqc{Rq.w, -Rq.x, -Rq.y, -Rq.z};
        const Q Rdc{Rdv.x, -Rdv.y, -Rdv.z, -Rdv.w};
        const float i0 = __expf(-log_gauss[b * 3 + 0]);
        const float i1 = __expf(-log_gauss[b * 3 + 1]);
        const float i2 = __expf(-log_gauss[b * 3 + 2]);
        const Q tqb = qmul(Rdc, Rq);
        const float qw = Rqc.w, qx = Rqc.x, qy = Rqc.y, qz = Rqc.z;
        const float r00 = 1.f - 2.f*(qy*qy + qz*qz), r01 = 2.f*(qx*qy - qw*qz), r02 = 2.f*(qx*qz + qw*qy);
        const float r10 = 2.f*(qx*qy + qw*qz), r11 = 1.f - 2.f*(qx*qx + qz*qz), r12 = 2.f*(qy*qz - qw*qx);
        const float r20 = 2.f*(qx*qz - qw*qy), r21 = 2.f*(qy*qz + qw*qx), r22 = 1.f - 2.f*(qx*qx + qy*qy);
        const float g00 = r00*i0, g01 = r01*i0, g02 = r02*i0;
        const float g10 = r10*i1, g11 = r11*i1, g12 = r12*i1;
        const float g20 = r20*i2, g21 = r21*i2, g22 = r22*i2;
        const float u0 = 2.f*tqb.x*i0, u1 = 2.f*tqb.y*i1, u2 = 2.f*tqb.z*i2;
        const float c = LOG2E;
        kK[b][0] = -0.5f*c*(g00*g00 + g10*g10 + g20*g20);
        kK[b][1] = -0.5f*c*(g01*g01 + g11*g11 + g21*g21);
        kK[b][2] = -0.5f*c*(g02*g02 + g12*g12 + g22*g22);
        kK[b][3] = -c*(g00*g01 + g10*g11 + g20*g21);
        kK[b][4] = -c*(g00*g02 + g10*g12 + g20*g22);
        kK[b][5] = -c*(g01*g02 + g11*g12 + g21*g22);
        kK[b][6] = -c*(g00*u0 + g10*u1 + g20*u2);
        kK[b][7] = -c*(g01*u0 + g11*u1 + g21*u2);
        kK[b][8] = -c*(g02*u0 + g12*u1 + g22*u2);
        kK[b][9] = -0.5f*c*(u0*u0 + u1*u1 + u2*u2);
    }

    // ---------- phase 1: se3 records (16 m x 25 bones = 400; threads do 1-2 each) ----------
    Q se_r1{0,0,0,0}, se_d1{0,0,0,0}, se_r2{0,0,0,0}, se_d2{0,0,0,0};
    int ms1 = 0, b1 = 0, ms2 = 0, b2 = 0;
    {
        const int r = t;                      // record 1: always
        ms1 = r / NB; b1 = r - ms1 * NB;
        const int gbase = (m0 * NB + r) * 4;
        const float4 Tqv = *reinterpret_cast<const float4*>(t_qr + gbase);
        const float4 Tdv = *reinterpret_cast<const float4*>(t_qd + gbase);
        const float4 Rqv = *reinterpret_cast<const float4*>(rest_qr + b1 * 4);
        const float4 Rdv = *reinterpret_cast<const float4*>(rest_qd + b1 * 4);
        const Q Tq{Tqv.x, Tqv.y, Tqv.z, Tqv.w};
        const Q Td{Tdv.x, Tdv.y, Tdv.z, Tdv.w};
        const Q Rq{Rqv.x, Rqv.y, Rqv.z, Rqv.w};
        const Q Rqc{Rq.w, -Rq.x, -Rq.y, -Rq.z};
        const Q Rdc{Rdv.x, -Rdv.y, -Rdv.z, -Rdv.w};
        se_r1 = qmul(Tq, Rqc);
        const Q a1 = qmul(Tq, Rdc);
        const Q a2 = qmul(Td, Rqc);
        se_d1 = Q{a1.w + a2.w, a1.x + a2.x, a1.y + a2.y, a1.z + a2.z};
        if (b1 == 0) *reinterpret_cast<float4*>(sref[ms1]) = make_float4(se_r1.w, se_r1.x, se_r1.y, se_r1.z);
    }
    const bool has2 = (t + 256) < (MPB * NB);
    if (has2) {                               // record 2: threads 0..143
        const int r = t + 256;
        ms2 = r / NB; b2 = r - ms2 * NB;
        const int gbase = (m0 * NB + r) * 4;
        const float4 Tqv = *reinterpret_cast<const float4*>(t_qr + gbase);
        const float4 Tdv = *reinterpret_cast<const float4*>(t_qd + gbase);
        const float4 Rqv = *reinterpret_cast<const float4*>(rest_qr + b2 * 4);
        const float4 Rdv = *reinterpret_cast<const float4*>(rest_qd + b2 * 4);
        const Q Tq{Tqv.x, Tqv.y, Tqv.z, Tqv.w};
        const Q Td{Tdv.x, Tdv.y, Tdv.z, Tdv.w};
        const Q Rq{Rqv.x, Rqv.y, Rqv.z, Rqv.w};
        const Q Rqc{Rq.w, -Rq.x, -Rq.y, -Rq.z};
        const Q Rdc{Rdv.x, -Rdv.y, -Rdv.z, -Rdv.w};
        se_r2 = qmul(Tq, Rqc);
        const Q a1 = qmul(Tq, Rdc);
        const Q a2 = qmul(Td, Rqc);
        se_d2 = Q{a1.w + a2.w, a1.x + a2.x, a1.y + a2.y, a1.z + a2.z};
        if (b2 == 0) *reinterpret_cast<float4*>(sref[ms2]) = make_float4(se_r2.w, se_r2.x, se_r2.y, se_r2.z);
    }
    __syncthreads();

    {   // sign-fix + pack to fp16
        const float4 rf = *reinterpret_cast<const float4*>(sref[ms1]);
        const float d0 = se_r1.w*rf.x + se_r1.x*rf.y + se_r1.y*rf.z + se_r1.z*rf.w;
        const float sg = (d0 < 0.f) ? -1.f : 1.f;
        qQ[ms1][b1][0] = pk_rn(sg*se_r1.w, sg*se_r1.x);
        qQ[ms1][b1][1] = pk_rn(sg*se_r1.y, sg*se_r1.z);
        qQ[ms1][b1][2] = pk_rn(sg*se_d1.w, sg*se_d1.x);
        qQ[ms1][b1][3] = pk_rn(sg*se_d1.y, sg*se_d1.z);
    }
    if (has2) {
        const float4 rf = *reinterpret_cast<const float4*>(sref[ms2]);
        const float d0 = se_r2.w*rf.x + se_r2.x*rf.y + se_r2.y*rf.z + se_r2.z*rf.w;
        const float sg = (d0 < 0.f) ? -1.f : 1.f;
        qQ[ms2][b2][0] = pk_rn(sg*se_r2.w, sg*se_r2.x);
        qQ[ms2][b2][1] = pk_rn(sg*se_r2.y, sg*se_r2.z);
        qQ[ms2][b2][2] = pk_rn(sg*se_d2.w, sg*se_d2.x);
        qQ[ms2][b2][3] = pk_rn(sg*se_d2.y, sg*se_d2.z);
    }
    __syncthreads();

    // ---------- phase 2: main loop; thread -> (m_sub, 4 consecutive points) ----------
    const int m_sub = t >> 4;                 // 16 threads per m
    const int pt0   = (t & 15) * PPT;
    const int m     = m0 + m_sub;
    const int pbase = (m * NN + pt0) * 3;

    const float4 v0 = *reinterpret_cast<const float4*>(xyz + pbase);
    const float4 v1 = *reinterpret_cast<const float4*>(xyz + pbase + 4);
    const float4 v2 = *reinterpret_cast<const float4*>(xyz + pbase + 8);
    float px[PPT], py[PPT], pz[PPT];
    px[0]=v0.x; py[0]=v0.y; pz[0]=v0.z;
    px[1]=v0.w; py[1]=v1.x; pz[1]=v1.y;
    px[2]=v1.z; py[2]=v1.w; pz[2]=v2.x;
    px[3]=v2.y; py[3]=v2.z; pz[3]=v2.w;

    float fxx[PPT], fyy[PPT], fzz[PPT], fxy[PPT], fxz[PPT], fyz[PPT];
#pragma unroll
    for (int p = 0; p < PPT; ++p) {
        fxx[p]=px[p]*px[p]; fyy[p]=py[p]*py[p]; fzz[p]=pz[p]*pz[p];
        fxy[p]=px[p]*py[p]; fxz[p]=px[p]*pz[p]; fyz[p]=py[p]*pz[p];
    }

    float lg[PPT][NB];
    float mx[PPT] = {-3.4e38f, -3.4e38f, -3.4e38f, -3.4e38f};
#pragma unroll
    for (int b = 0; b < NB; ++b) {
        const float k0=kK[b][0], k1=kK[b][1], k2=kK[b][2], k3=kK[b][3], k4=kK[b][4];
        const float k5=kK[b][5], k6=kK[b][6], k7=kK[b][7], k8=kK[b][8], k9=kK[b][9];
#pragma unroll
        for (int p = 0; p < PPT; ++p) {
            float s = fmaf(k8, pz[p], k9);
            s = fmaf(k7, py[p], s);
            s = fmaf(k6, px[p], s);
            s = fmaf(k5, fyz[p], s);
            s = fmaf(k4, fxz[p], s);
            s = fmaf(k3, fxy[p], s);
            s = fmaf(k2, fzz[p], s);
            s = fmaf(k1, fyy[p], s);
            s = fmaf(k0, fxx[p], s);
            lg[p][b] = s;
            mx[p] = fmaxf(mx[p], s);
        }
    }

    const __half2 hz = __floats2half2_rn(0.f, 0.f);
    __half2 acc[PPT][4];
#pragma unroll
    for (int p = 0; p < PPT; ++p) { acc[p][0]=hz; acc[p][1]=hz; acc[p][2]=hz; acc[p][3]=hz; }

#pragma unroll
    for (int b = 0; b < NB; ++b) {
        const uint4 qv = *reinterpret_cast<const uint4*>(&qQ[m_sub][b][0]);  // 1x ds_read_b128
        const __half2 h0 = bc_h2(qv.x), h1 = bc_h2(qv.y), h2 = bc_h2(qv.z), h3 = bc_h2(qv.w);
#pragma unroll
        for (int p = 0; p < PPT; ++p) {
            const float e = __builtin_amdgcn_exp2f(lg[p][b] - mx[p]);
            const __half2 e2 = pk_rtz(e, e);
            acc[p][0] = __hfma2(e2, h0, acc[p][0]);
            acc[p][1] = __hfma2(e2, h1, acc[p][1]);
            acc[p][2] = __hfma2(e2, h2, acc[p][2]);
            acc[p][3] = __hfma2(e2, h3, acc[p][3]);
        }
    }

    float o[12];
#pragma unroll
    for (int p = 0; p < PPT; ++p) {
        const float aw = __low2float(acc[p][0]), ax = __high2float(acc[p][0]);
        const float ay = __low2float(acc[p][1]), az = __high2float(acc[p][1]);
        const float bw = __low2float(acc[p][2]), bx = __high2float(acc[p][2]);
        const float by = __low2float(acc[p][3]), bz = __high2float(acc[p][3]);

        const float inv = rsqrtf(aw*aw + ax*ax + ay*ay + az*az);
        const Q qr{aw*inv, ax*inv, ay*inv, az*inv};
        const Q qd{bw*inv, bx*inv, by*inv, bz*inv};
        const Q qrc{qr.w, -qr.x, -qr.y, -qr.z};
        const Q tq = qmul(qd, qrc);

        const float uvx = qr.y*pz[p] - qr.z*py[p];
        const float uvy = qr.z*px[p] - qr.x*pz[p];
        const float uvz = qr.x*py[p] - qr.y*px[p];
        const float cx = qr.y*uvz - qr.z*uvy;
        const float cy = qr.z*uvx - qr.x*uvz;
        const float cz = qr.x*uvy - qr.y*uvx;

        o[p*3+0] = px[p] + 2.f*(qr.w*uvx + cx) + 2.f*tq.x;
        o[p*3+1] = py[p] + 2.f*(qr.w*uvy + cy) + 2.f*tq.y;
        o[p*3+2] = pz[p] + 2.f*(qr.w*uvz + cz) + 2.f*tq.z;
    }

    *reinterpret_cast<float4*>(out + pbase)     = make_float4(o[0], o[1], o[2],  o[3]);
    *reinterpret_cast<float4*>(out + pbase + 4) = make_float4(o[4], o[5], o[6],  o[7]);
    *reinterpret_cast<float4*>(out + pbase + 8) = make_float4(o[8], o[9], o[10], o[11]);
}

extern "C" void kernel_launch(void* const* d_in, const int* in_sizes, int n_in,
                              void* d_out, int out_size, void* d_ws, size_t ws_size,
                              hipStream_t stream) {
    const float* xyz       = (const float*)d_in[0];
    const float* t_qr      = (const float*)d_in[1];
    const float* t_qd      = (const float*)d_in[2];
    const float* rest_qr   = (const float*)d_in[3];
    const float* rest_qd   = (const float*)d_in[4];
    const float* log_gauss = (const float*)d_in[5];
    float* out = (float*)d_out;

    hipLaunchKernelGGL(skin_kernel, dim3(MM / MPB), dim3(256), 0, stream,
                       xyz, t_qr, t_qd, rest_qr, rest_qd, log_gauss, out);
}